// Round 3
// baseline (1207.639 us; speedup 1.0000x reference)
//
#include <hip/hip_runtime.h>

#define EN 500000
#define NT 7813              // (EN+63)/64
#define XLIM (EN*64 - 4)     // last valid float4 start (float index)

// ---- ws float offsets (small constants only, ~145 KB) ----
#define SEC1T  0
#define SEC2   4096
#define SEC2T  8192
#define M1_    12288
#define M2T_   16384
#define M3T_   20480
#define WOUTT  24576
#define G2_    28672
#define G3_    32768
#define C1_    36864
#define C2_    36928
#define C3_    36992

// ---- big partial buffers live in d_out (overwritten by k_p5 at the end) ----
#define NB1 512              // k_accum grid
#define NB2 512              // k_p3 grid
#define PSL 4160             // partial slice: 4096 acc + 64 colsum
#define P2_OFF 2129920       // NB1*PSL

__device__ __forceinline__ float leaky1(float v) {
    return v >= 0.f ? v : 0.01f * v;
}

__device__ __forceinline__ void gl_lds16(const float* g, float* l) {
    __builtin_amdgcn_global_load_lds(
        (const __attribute__((address_space(1))) unsigned int*)g,
        (__attribute__((address_space(3))) unsigned int*)l, 16, 0, 0);
}

// ---------------------------------------------------------------------------
// k_accum: part[blk] = { raw[s][d] = sum_e w[e,s]*x[e,d] ; colsum[s] } over
// this block's grid-strided tiles. global_load_lds dbuf staging (linear LDS),
// 8x8 register tile, 4-way e-split across waves, in-block LDS reduce
// (reduce buffers ALIAS the dead staging buffers -> 64 KiB total, 2 blk/CU).
// ---------------------------------------------------------------------------
__global__ __launch_bounds__(256, 2) void k_accum(
    const float* __restrict__ w, const float* __restrict__ x,
    float* __restrict__ part)
{
    __shared__ float wbuf[2][4096];
    __shared__ float xbuf[2][4096];
    const int t    = threadIdx.x;
    const int wv   = t >> 6;
    const int lane = t & 63;
    const int sg   = (t >> 3) & 7;
    const int dg   = t & 7;

    float acc[8][8];
#pragma unroll
    for (int i = 0; i < 8; ++i)
#pragma unroll
        for (int j = 0; j < 8; ++j) acc[i][j] = 0.f;
    float csum[8];
#pragma unroll
    for (int i = 0; i < 8; ++i) csum[i] = 0.f;

    int tile = blockIdx.x;
    {   // prologue stage into buf 0
        const int base = tile << 6;
#pragma unroll
        for (int u = 0; u < 4; ++u) {
            const int fo = ((wv << 2) + u) << 8;      // wave-uniform lds offset
            int gi = base * 64 + fo + (lane << 2);
            gi = gi > XLIM ? XLIM : gi;               // clamp (guarded later)
            gl_lds16(w + gi, &wbuf[0][fo]);
            gl_lds16(x + gi, &xbuf[0][fo]);
        }
    }
    __syncthreads();
    int cur = 0;
    while (tile < NT) {
        const int nxt = tile + gridDim.x;
        if (nxt < NT) {
            const int base = nxt << 6;
#pragma unroll
            for (int u = 0; u < 4; ++u) {
                const int fo = ((wv << 2) + u) << 8;
                int gi = base * 64 + fo + (lane << 2);
                gi = gi > XLIM ? XLIM : gi;
                gl_lds16(w + gi, &wbuf[cur ^ 1][fo]);
                gl_lds16(x + gi, &xbuf[cur ^ 1][fo]);
            }
        }
        const int base = tile << 6;
        const float* wb = wbuf[cur];
        const float* xb = xbuf[cur];
#pragma unroll 4
        for (int i = 0; i < 16; ++i) {
            const int e = (wv << 4) + i;              // wave-uniform
            if (base + e < EN) {
                const float4 wa = *(const float4*)(wb + e * 64 + sg * 8);
                const float4 wc = *(const float4*)(wb + e * 64 + sg * 8 + 4);
                const float4 xa = *(const float4*)(xb + e * 64 + dg * 8);
                const float4 xc = *(const float4*)(xb + e * 64 + dg * 8 + 4);
                const float wr[8] = {wa.x, wa.y, wa.z, wa.w, wc.x, wc.y, wc.z, wc.w};
                const float xr[8] = {xa.x, xa.y, xa.z, xa.w, xc.x, xc.y, xc.z, xc.w};
#pragma unroll
                for (int a = 0; a < 8; ++a) {
#pragma unroll
                    for (int b = 0; b < 8; ++b)
                        acc[a][b] = fmaf(wr[a], xr[b], acc[a][b]);
                    csum[a] += wr[a];
                }
            }
        }
        __syncthreads();   // drains gl_lds prefetch + guards buffers
        cur ^= 1;
        tile = nxt;
    }
    // cross-wave (e-split) reduce via LDS (reuse staging buffers), then store
    float* redp = &wbuf[0][0];        // 4096 floats
    float* cbuf = &wbuf[1][0];        // 64 floats used
    const int r0 = sg * 8, c0 = dg * 8;
#pragma unroll
    for (int ph = 1; ph < 4; ++ph) {
        if (wv == ph) {
#pragma unroll
            for (int i = 0; i < 8; ++i) {
                *(float4*)(redp + (r0 + i) * 64 + c0) =
                    make_float4(acc[i][0], acc[i][1], acc[i][2], acc[i][3]);
                *(float4*)(redp + (r0 + i) * 64 + c0 + 4) =
                    make_float4(acc[i][4], acc[i][5], acc[i][6], acc[i][7]);
            }
            if (dg == 0) {
#pragma unroll
                for (int i = 0; i < 8; ++i) cbuf[r0 + i] = csum[i];
            }
        }
        __syncthreads();
        if (wv == 0) {
#pragma unroll
            for (int i = 0; i < 8; ++i)
#pragma unroll
                for (int j = 0; j < 8; ++j)
                    acc[i][j] += redp[(r0 + i) * 64 + c0 + j];
            if (dg == 0) {
#pragma unroll
                for (int i = 0; i < 8; ++i) csum[i] += cbuf[r0 + i];
            }
        }
        __syncthreads();
    }
    if (wv == 0) {
        float* slice = part + (size_t)blockIdx.x * PSL;
#pragma unroll
        for (int i = 0; i < 8; ++i) {
            *(float4*)(slice + (r0 + i) * 64 + c0) =
                make_float4(acc[i][0], acc[i][1], acc[i][2], acc[i][3]);
            *(float4*)(slice + (r0 + i) * 64 + c0 + 4) =
                make_float4(acc[i][4], acc[i][5], acc[i][6], acc[i][7]);
        }
        if (dg == 0) {
#pragma unroll
            for (int i = 0; i < 8; ++i) slice[4096 + r0 + i] = csum[i];
        }
    }
}

// ---------------------------------------------------------------------------
// k_p3: per 64-entity tile:
//   stepA: lane owns entity row; wave owns 16 sectors (sec1^T rows via
//          wave-uniform scalar loads). p = exp(x . sec1) max-free.
//   stepB: raw2 += p^T @ x with 8x8 register tiles; sumexp cols.
// x-tile reg-staged (T14 issue-early/write-late) into pad-68 LDS dbuf.
// Reduce buffers alias xbuf (dead after loop) -> 52 KiB LDS.
// ---------------------------------------------------------------------------
__global__ __launch_bounds__(256, 2) void k_p3(
    const float* __restrict__ x, const float* __restrict__ s1t,
    float* __restrict__ part)
{
    __shared__ float xbuf[2][64 * 68];
    __shared__ float pt[64 * 68];
    const int t    = threadIdx.x;
    const int wv   = t >> 6;
    const int lane = t & 63;
    const int wu   = __builtin_amdgcn_readfirstlane(wv);
    const int sg   = (t >> 3) & 7;
    const int dg   = t & 7;

    float acc[8][8];
#pragma unroll
    for (int i = 0; i < 8; ++i)
#pragma unroll
        for (int j = 0; j < 8; ++j) acc[i][j] = 0.f;
    float sume[8];
#pragma unroll
    for (int i = 0; i < 8; ++i) sume[i] = 0.f;

    int tile = blockIdx.x;
    float4 gx[4];
    {   // prologue: load + write tile0
        const int base = tile << 6;
#pragma unroll
        for (int u = 0; u < 4; ++u) {
            const int f = t + (u << 8);
            const int ge = base + (f >> 4);
            gx[u] = (ge < EN) ? *(const float4*)(x + (size_t)ge * 64 + (f & 15) * 4)
                              : make_float4(0.f, 0.f, 0.f, 0.f);
        }
#pragma unroll
        for (int u = 0; u < 4; ++u) {
            const int f = t + (u << 8);
            *(float4*)(&xbuf[0][(f >> 4) * 68 + (f & 15) * 4]) = gx[u];
        }
    }
    __syncthreads();
    int cur = 0;
    while (tile < NT) {
        const int nxt = tile + gridDim.x;
        if (nxt < NT) {       // issue next-tile loads early; write after stepB
            const int base = nxt << 6;
#pragma unroll
            for (int u = 0; u < 4; ++u) {
                const int f = t + (u << 8);
                const int ge = base + (f >> 4);
                gx[u] = (ge < EN) ? *(const float4*)(x + (size_t)ge * 64 + (f & 15) * 4)
                                  : make_float4(0.f, 0.f, 0.f, 0.f);
            }
        }
        const int base = tile << 6;
        const bool ev = (base + lane) < EN;
        // ---- stepA: sc[j] = sum_k x[lane,k] * sec1T[k][wu*16+j] ----
        float sc[16];
#pragma unroll
        for (int j = 0; j < 16; ++j) sc[j] = 0.f;
#pragma unroll 4
        for (int kb = 0; kb < 16; ++kb) {
            const float4 xa = *(const float4*)(&xbuf[cur][lane * 68 + kb * 4]);
            const float xk[4] = {xa.x, xa.y, xa.z, xa.w};
#pragma unroll
            for (int r = 0; r < 4; ++r) {
                const float* srow = s1t + (kb * 4 + r) * 64 + wu * 16;
                const float xv = xk[r];
#pragma unroll
                for (int j = 0; j < 16; ++j) sc[j] = fmaf(xv, srow[j], sc[j]);
            }
        }
        float pe[16];
#pragma unroll
        for (int j = 0; j < 16; ++j) pe[j] = ev ? __expf(sc[j]) : 0.f;
#pragma unroll
        for (int q = 0; q < 4; ++q)
            *(float4*)(&pt[lane * 68 + wu * 16 + q * 4]) =
                make_float4(pe[q * 4], pe[q * 4 + 1], pe[q * 4 + 2], pe[q * 4 + 3]);
        __syncthreads();
        // ---- stepB: acc[a][b] += p[e, sg*8+a] * x[e, dg*8+b] ----
#pragma unroll 4
        for (int i = 0; i < 16; ++i) {
            const int e = (wv << 4) + i;
            if (base + e < EN) {
                const float4 pa = *(const float4*)(&pt[e * 68 + sg * 8]);
                const float4 pb = *(const float4*)(&pt[e * 68 + sg * 8 + 4]);
                const float4 xa = *(const float4*)(&xbuf[cur][e * 68 + dg * 8]);
                const float4 xc = *(const float4*)(&xbuf[cur][e * 68 + dg * 8 + 4]);
                const float pr[8] = {pa.x, pa.y, pa.z, pa.w, pb.x, pb.y, pb.z, pb.w};
                const float xr[8] = {xa.x, xa.y, xa.z, xa.w, xc.x, xc.y, xc.z, xc.w};
#pragma unroll
                for (int a = 0; a < 8; ++a) {
#pragma unroll
                    for (int b = 0; b < 8; ++b)
                        acc[a][b] = fmaf(pr[a], xr[b], acc[a][b]);
                    sume[a] += pr[a];
                }
            }
        }
        if (nxt < NT) {       // write-late: loads had stepA+stepB to land
#pragma unroll
            for (int u = 0; u < 4; ++u) {
                const int f = t + (u << 8);
                *(float4*)(&xbuf[cur ^ 1][(f >> 4) * 68 + (f & 15) * 4]) = gx[u];
            }
        }
        __syncthreads();
        cur ^= 1;
        tile = nxt;
    }
    // reduce (reuse xbuf) + per-block partial store
    float* redp = &xbuf[0][0];
    float* cbuf = redp + 4096;
    const int r0 = sg * 8, c0 = dg * 8;
#pragma unroll
    for (int ph = 1; ph < 4; ++ph) {
        if (wv == ph) {
#pragma unroll
            for (int i = 0; i < 8; ++i) {
                *(float4*)(redp + (r0 + i) * 64 + c0) =
                    make_float4(acc[i][0], acc[i][1], acc[i][2], acc[i][3]);
                *(float4*)(redp + (r0 + i) * 64 + c0 + 4) =
                    make_float4(acc[i][4], acc[i][5], acc[i][6], acc[i][7]);
            }
            if (dg == 0) {
#pragma unroll
                for (int i = 0; i < 8; ++i) cbuf[r0 + i] = sume[i];
            }
        }
        __syncthreads();
        if (wv == 0) {
#pragma unroll
            for (int i = 0; i < 8; ++i)
#pragma unroll
                for (int j = 0; j < 8; ++j)
                    acc[i][j] += redp[(r0 + i) * 64 + c0 + j];
            if (dg == 0) {
#pragma unroll
                for (int i = 0; i < 8; ++i) sume[i] += cbuf[r0 + i];
            }
        }
        __syncthreads();
    }
    if (wv == 0) {
        float* slice = part + (size_t)blockIdx.x * PSL;
#pragma unroll
        for (int i = 0; i < 8; ++i) {
            *(float4*)(slice + (r0 + i) * 64 + c0) =
                make_float4(acc[i][0], acc[i][1], acc[i][2], acc[i][3]);
            *(float4*)(slice + (r0 + i) * 64 + c0 + 4) =
                make_float4(acc[i][4], acc[i][5], acc[i][6], acc[i][7]);
        }
        if (dg == 0) {
#pragma unroll
            for (int i = 0; i < 8; ++i) slice[4096 + r0 + i] = sume[i];
        }
    }
}

// ---------------------------------------------------------------------------
// k_p5: thread-per-entity, phased for VGPR<=~150.
//   ph1: tt = x@sec2^T (rows via s_load); softmax; inv -> LDS [s][tid]
//        (LDS = only runtime-indexable home; reg array would scratch-spill).
//   ph2: o1 = inv@G2, o2 = inv@G3 (runtime s-loop, I$-resident body).
//   ph3: o2 += x@Wout^T (x reloaded, L2-hot). Outputs leaky(+bias).
// ---------------------------------------------------------------------------
__global__ __launch_bounds__(256, 2) void k_p5(
    const float* __restrict__ x, const float* __restrict__ s2t,
    const float* __restrict__ G2, const float* __restrict__ G3,
    const float* __restrict__ wot, const float* __restrict__ c2,
    const float* __restrict__ c3, float* __restrict__ out1,
    float* __restrict__ out2)
{
    __shared__ float inv_lds[64 * 256];   // per-thread scratch, [s][tid]
    const int tid = threadIdx.x;
    const int e = blockIdx.x * 256 + tid;
    const bool ev = e < EN;
    const float* xe = x + (size_t)e * 64;

    float tt[64];
#pragma unroll
    for (int s = 0; s < 64; ++s) tt[s] = 0.f;
    for (int kb = 0; kb < 4; ++kb) {
        float xs[16];
#pragma unroll
        for (int u = 0; u < 4; ++u) {
            const float4 v = ev ? *(const float4*)(xe + kb * 16 + u * 4)
                                : make_float4(0.f, 0.f, 0.f, 0.f);
            xs[u * 4 + 0] = v.x; xs[u * 4 + 1] = v.y;
            xs[u * 4 + 2] = v.z; xs[u * 4 + 3] = v.w;
        }
#pragma unroll
        for (int kk = 0; kk < 16; ++kk) {
            const float* row = s2t + (kb * 16 + kk) * 64;
            const float xv = xs[kk];
#pragma unroll
            for (int s = 0; s < 64; ++s) tt[s] = fmaf(xv, row[s], tt[s]);
        }
    }
    float m = tt[0];
#pragma unroll
    for (int s = 1; s < 64; ++s) m = fmaxf(m, tt[s]);
    float Z = 0.f;
#pragma unroll
    for (int s = 0; s < 64; ++s) { tt[s] = __expf(tt[s] - m); Z += tt[s]; }
    const float rZ = 1.f / Z;
#pragma unroll
    for (int s = 0; s < 64; ++s) inv_lds[s * 256 + tid] = tt[s] * rZ;

    float o1[64], o2[64];
#pragma unroll
    for (int d = 0; d < 64; ++d) { o1[d] = 0.f; o2[d] = 0.f; }
    for (int s = 0; s < 64; ++s) {            // runtime loop, I$-resident body
        const float iv = inv_lds[s * 256 + tid];
        const float* g2r = G2 + s * 64;
        const float* g3r = G3 + s * 64;
#pragma unroll
        for (int d = 0; d < 64; ++d) o1[d] = fmaf(iv, g2r[d], o1[d]);
#pragma unroll
        for (int d = 0; d < 64; ++d) o2[d] = fmaf(iv, g3r[d], o2[d]);
    }
    if (ev) {
        float4* o1p = (float4*)(out1 + (size_t)e * 64);
#pragma unroll
        for (int q = 0; q < 16; ++q) {
            float4 v;
            v.x = leaky1(o1[q * 4 + 0] + c2[q * 4 + 0]);
            v.y = leaky1(o1[q * 4 + 1] + c2[q * 4 + 1]);
            v.z = leaky1(o1[q * 4 + 2] + c2[q * 4 + 2]);
            v.w = leaky1(o1[q * 4 + 3] + c2[q * 4 + 3]);
            o1p[q] = v;
        }
    }
    for (int kb = 0; kb < 4; ++kb) {
        float xs[16];
#pragma unroll
        for (int u = 0; u < 4; ++u) {
            const float4 v = ev ? *(const float4*)(xe + kb * 16 + u * 4)
                                : make_float4(0.f, 0.f, 0.f, 0.f);
            xs[u * 4 + 0] = v.x; xs[u * 4 + 1] = v.y;
            xs[u * 4 + 2] = v.z; xs[u * 4 + 3] = v.w;
        }
#pragma unroll
        for (int kk = 0; kk < 16; ++kk) {
            const float* row = wot + (kb * 16 + kk) * 64;
            const float xv = xs[kk];
#pragma unroll
            for (int d = 0; d < 64; ++d) o2[d] = fmaf(xv, row[d], o2[d]);
        }
    }
    if (ev) {
        float4* o2p = (float4*)(out2 + (size_t)e * 64);
#pragma unroll
        for (int q = 0; q < 16; ++q) {
            float4 v;
            v.x = leaky1(o2[q * 4 + 0] + c3[q * 4 + 0]);
            v.y = leaky1(o2[q * 4 + 1] + c3[q * 4 + 1]);
            v.z = leaky1(o2[q * 4 + 2] + c3[q * 4 + 2]);
            v.w = leaky1(o2[q * 4 + 3] + c3[q * 4 + 3]);
            o2p[q] = v;
        }
    }
}

// ---------------------------------------------------------------------------
// partial-reduce + normalize kernels (4096 threads each)
// ---------------------------------------------------------------------------
__global__ void k_norm1(const float* __restrict__ part, float* __restrict__ ws)
{
    const int gid = blockIdx.x * 256 + threadIdx.x;
    const int s = gid >> 6, d = gid & 63;
    float raw = 0.f, cs = 0.f;
#pragma unroll 16
    for (int b = 0; b < NB1; ++b) {
        raw += part[(size_t)b * PSL + gid];
        cs  += part[(size_t)b * PSL + 4096 + s];
    }
    ws[SEC1T + d * 64 + s] = raw / cs;    // transposed for k_p3 stepA
}

__global__ void k_norm2(const float* __restrict__ part, float* __restrict__ ws)
{
    const int gid = blockIdx.x * 256 + threadIdx.x;
    const int s = gid >> 6, d = gid & 63;
    float raw = 0.f, se = 0.f;
#pragma unroll 16
    for (int b = 0; b < NB2; ++b) {
        raw += part[(size_t)b * PSL + gid];
        se  += part[(size_t)b * PSL + 4096 + s];
    }
    const float v = raw / se;
    ws[SEC2 + gid] = v;
    ws[SEC2T + d * 64 + s] = v;
}

// ---------------------------------------------------------------------------
// tiny prep kernels (64x64 weight folds)
// ---------------------------------------------------------------------------
__global__ void k_prep1(const float* __restrict__ W_ent, const float* __restrict__ b_ent,
                        const float* __restrict__ Wsi, const float* __restrict__ bsi,
                        const float* __restrict__ Wso, const float* __restrict__ bso,
                        const float* __restrict__ Wout,
                        float* __restrict__ ws)
{
    const int gid = blockIdx.x * 256 + threadIdx.x;
    if (gid < 4096) {                       // M1[d][m] = (Wsi@W_ent)[d][m]
        const int d = gid >> 6, mm = gid & 63;
        float s = 0.f;
        for (int k = 0; k < 64; ++k) s = fmaf(Wsi[d * 64 + k], W_ent[k * 64 + mm], s);
        ws[M1_ + gid] = s;
    } else if (gid < 8192) {                // M2T[m][d] = (Wso@W_ent)[d][m]
        const int i = gid - 4096, mm = i >> 6, d = i & 63;
        float s = 0.f;
        for (int j = 0; j < 64; ++j) s = fmaf(W_ent[j * 64 + mm], Wso[d * 64 + j], s);
        ws[M2T_ + i] = s;
    } else if (gid < 12288) {               // WoutT[k][d] = Wout[d][k]
        const int i = gid - 8192, k = i >> 6, d = i & 63;
        ws[WOUTT + i] = Wout[d * 64 + k];
    } else if (gid < 12352) {               // c1 = Wsi@b_ent + bsi
        const int d = gid - 12288;
        float s = bsi[d];
        for (int k = 0; k < 64; ++k) s = fmaf(Wsi[d * 64 + k], b_ent[k], s);
        ws[C1_ + d] = s;
    } else if (gid < 12416) {               // c2 = Wso@b_ent + bso
        const int d = gid - 12352;
        float s = bso[d];
        for (int k = 0; k < 64; ++k) s = fmaf(Wso[d * 64 + k], b_ent[k], s);
        ws[C2_ + d] = s;
    }
}

__global__ void k_prep2(const float* __restrict__ Wout, const float* __restrict__ bout,
                        float* __restrict__ ws)
{
    const int gid = blockIdx.x * 256 + threadIdx.x;
    const float* M1p = ws + M1_;
    if (gid < 4096) {                       // M3T[m][d] = (Wout@M1)[d][m]
        const int mm = gid >> 6, d = gid & 63;
        float s = 0.f;
        for (int j = 0; j < 64; ++j) s = fmaf(Wout[d * 64 + j], M1p[j * 64 + mm], s);
        ws[M3T_ + gid] = s;
    } else if (gid < 4160) {                // c3 = Wout@c1 + bout
        const int d = gid - 4096;
        const float* c1p = ws + C1_;
        float s = bout[d];
        for (int k = 0; k < 64; ++k) s = fmaf(Wout[d * 64 + k], c1p[k], s);
        ws[C3_ + d] = s;
    }
}

__global__ void k_prepG(float* __restrict__ ws)
{
    const int gid = blockIdx.x * 256 + threadIdx.x;  // 8192 threads
    const float* sec2 = ws + SEC2;
    if (gid < 4096) {                        // G2 = sec2 @ M2^T
        const int s = gid >> 6, d = gid & 63;
        const float* m2t = ws + M2T_;
        float a = 0.f;
        for (int k = 0; k < 64; ++k) a = fmaf(sec2[s * 64 + k], m2t[k * 64 + d], a);
        ws[G2_ + gid] = a;
    } else {                                 // G3 = sec2 @ M3^T
        const int i = gid - 4096, s = i >> 6, d = i & 63;
        const float* m3t = ws + M3T_;
        float a = 0.f;
        for (int k = 0; k < 64; ++k) a = fmaf(sec2[s * 64 + k], m3t[k * 64 + d], a);
        ws[G3_ + i] = a;
    }
}

extern "C" void kernel_launch(void* const* d_in, const int* in_sizes, int n_in,
                              void* d_out, int out_size, void* d_ws, size_t ws_size,
                              hipStream_t stream)
{
    const float* x     = (const float*)d_in[0];
    const float* e2s   = (const float*)d_in[1];
    const float* W_ent = (const float*)d_in[2];
    const float* b_ent = (const float*)d_in[3];
    const float* Wsi   = (const float*)d_in[4];
    const float* bsi   = (const float*)d_in[5];
    const float* Wso   = (const float*)d_in[6];
    const float* bso   = (const float*)d_in[7];
    const float* Wout  = (const float*)d_in[8];
    const float* bout  = (const float*)d_in[9];
    float* ws  = (float*)d_ws;
    float* out = (float*)d_out;

    (void)in_sizes; (void)n_in; (void)out_size; (void)ws_size;

    // big partial buffers live in d_out; k_p5 (last) fully overwrites d_out
    float* p1 = out;                 // NB1*PSL floats
    float* p2 = out + P2_OFF;        // NB2*PSL floats

    k_prep1<<<49, 256, 0, stream>>>(W_ent, b_ent, Wsi, bsi, Wso, bso, Wout, ws);
    k_prep2<<<17, 256, 0, stream>>>(Wout, bout, ws);
    k_accum<<<NB1, 256, 0, stream>>>(e2s, x, p1);
    k_norm1<<<16, 256, 0, stream>>>(p1, ws);
    k_p3<<<NB2, 256, 0, stream>>>(x, ws + SEC1T, p2);
    k_norm2<<<16, 256, 0, stream>>>(p2, ws);
    k_prepG<<<32, 256, 0, stream>>>(ws);
    k_p5<<<(EN + 255) / 256, 256, 0, stream>>>(x, ws + SEC2T, ws + G2_, ws + G3_,
                                               ws + WOUTT, ws + C2_, ws + C3_,
                                               out, out + (size_t)EN * 64);
}

// Round 4
// 966.186 us; speedup vs baseline: 1.2499x; 1.2499x over previous
//
#include <hip/hip_runtime.h>

#define EN 500000
#define NT 7813              // (EN+63)/64
#define XLIM (EN*64 - 4)     // last valid float4 start (float index)

// ---- ws float offsets (small constants only, ~145 KB) ----
#define SEC1T  0
#define SEC2   4096
#define SEC2T  8192
#define M1_    12288
#define M2T_   16384
#define M3T_   20480
#define WOUTT  24576
#define G2_    28672
#define G3_    32768
#define C1_    36864
#define C2_    36928
#define C3_    36992

// ---- big partial buffers live in d_out (overwritten by k_p5 at the end) ----
#define NB1 512              // k_accum grid
#define NB2 768              // k_p3 grid
#define PSL 4160             // partial slice: 4096 acc + 64 colsum
#define P2_OFF 2129920       // NB1*PSL

__device__ __forceinline__ float leaky1(float v) {
    return v >= 0.f ? v : 0.01f * v;
}

__device__ __forceinline__ void gl_lds16(const float* g, float* l) {
    __builtin_amdgcn_global_load_lds(
        (const __attribute__((address_space(1))) unsigned int*)g,
        (__attribute__((address_space(3))) unsigned int*)l, 16, 0, 0);
}

// ---------------------------------------------------------------------------
// k_accum: part[blk] = { raw[s][d] = sum_e w[e,s]*x[e,d] ; colsum[s] } over
// this block's grid-strided tiles. global_load_lds dbuf staging (linear LDS),
// 8x8 register tile, 4-way e-split across waves, in-block LDS reduce
// (reduce buffers alias dead staging buffers -> 64 KiB, 2 blk/CU).
// ---------------------------------------------------------------------------
__global__ __launch_bounds__(256, 2) void k_accum(
    const float* __restrict__ w, const float* __restrict__ x,
    float* __restrict__ part)
{
    __shared__ float wbuf[2][4096];
    __shared__ float xbuf[2][4096];
    const int t    = threadIdx.x;
    const int wv   = t >> 6;
    const int lane = t & 63;
    const int sg   = (t >> 3) & 7;
    const int dg   = t & 7;

    float acc[8][8];
#pragma unroll
    for (int i = 0; i < 8; ++i)
#pragma unroll
        for (int j = 0; j < 8; ++j) acc[i][j] = 0.f;
    float csum[8];
#pragma unroll
    for (int i = 0; i < 8; ++i) csum[i] = 0.f;

    int tile = blockIdx.x;
    {   // prologue stage into buf 0
        const int base = tile << 6;
#pragma unroll
        for (int u = 0; u < 4; ++u) {
            const int fo = ((wv << 2) + u) << 8;      // wave-uniform lds offset
            int gi = base * 64 + fo + (lane << 2);
            gi = gi > XLIM ? XLIM : gi;               // clamp (guarded later)
            gl_lds16(w + gi, &wbuf[0][fo]);
            gl_lds16(x + gi, &xbuf[0][fo]);
        }
    }
    __syncthreads();
    int cur = 0;
    while (tile < NT) {
        const int nxt = tile + gridDim.x;
        if (nxt < NT) {
            const int base = nxt << 6;
#pragma unroll
            for (int u = 0; u < 4; ++u) {
                const int fo = ((wv << 2) + u) << 8;
                int gi = base * 64 + fo + (lane << 2);
                gi = gi > XLIM ? XLIM : gi;
                gl_lds16(w + gi, &wbuf[cur ^ 1][fo]);
                gl_lds16(x + gi, &xbuf[cur ^ 1][fo]);
            }
        }
        const int base = tile << 6;
        const float* wb = wbuf[cur];
        const float* xb = xbuf[cur];
        if (base + 64 <= EN) {            // fast path: no per-e guard
#pragma unroll 4
            for (int i = 0; i < 16; ++i) {
                const int e = (wv << 4) + i;
                const float4 wa = *(const float4*)(wb + e * 64 + sg * 8);
                const float4 wc = *(const float4*)(wb + e * 64 + sg * 8 + 4);
                const float4 xa = *(const float4*)(xb + e * 64 + dg * 8);
                const float4 xc = *(const float4*)(xb + e * 64 + dg * 8 + 4);
                const float wr[8] = {wa.x, wa.y, wa.z, wa.w, wc.x, wc.y, wc.z, wc.w};
                const float xr[8] = {xa.x, xa.y, xa.z, xa.w, xc.x, xc.y, xc.z, xc.w};
#pragma unroll
                for (int a = 0; a < 8; ++a) {
#pragma unroll
                    for (int b = 0; b < 8; ++b)
                        acc[a][b] = fmaf(wr[a], xr[b], acc[a][b]);
                    csum[a] += wr[a];
                }
            }
        } else {
#pragma unroll 4
            for (int i = 0; i < 16; ++i) {
                const int e = (wv << 4) + i;
                if (base + e < EN) {
                    const float4 wa = *(const float4*)(wb + e * 64 + sg * 8);
                    const float4 wc = *(const float4*)(wb + e * 64 + sg * 8 + 4);
                    const float4 xa = *(const float4*)(xb + e * 64 + dg * 8);
                    const float4 xc = *(const float4*)(xb + e * 64 + dg * 8 + 4);
                    const float wr[8] = {wa.x, wa.y, wa.z, wa.w, wc.x, wc.y, wc.z, wc.w};
                    const float xr[8] = {xa.x, xa.y, xa.z, xa.w, xc.x, xc.y, xc.z, xc.w};
#pragma unroll
                    for (int a = 0; a < 8; ++a) {
#pragma unroll
                        for (int b = 0; b < 8; ++b)
                            acc[a][b] = fmaf(wr[a], xr[b], acc[a][b]);
                        csum[a] += wr[a];
                    }
                }
            }
        }
        __syncthreads();   // drains gl_lds prefetch + guards buffers
        cur ^= 1;
        tile = nxt;
    }
    // cross-wave (e-split) reduce via LDS (reuse staging buffers), then store
    float* redp = &wbuf[0][0];        // 4096 floats
    float* cbuf = &wbuf[1][0];        // 64 floats used
    const int r0 = sg * 8, c0 = dg * 8;
#pragma unroll
    for (int ph = 1; ph < 4; ++ph) {
        if (wv == ph) {
#pragma unroll
            for (int i = 0; i < 8; ++i) {
                *(float4*)(redp + (r0 + i) * 64 + c0) =
                    make_float4(acc[i][0], acc[i][1], acc[i][2], acc[i][3]);
                *(float4*)(redp + (r0 + i) * 64 + c0 + 4) =
                    make_float4(acc[i][4], acc[i][5], acc[i][6], acc[i][7]);
            }
            if (dg == 0) {
#pragma unroll
                for (int i = 0; i < 8; ++i) cbuf[r0 + i] = csum[i];
            }
        }
        __syncthreads();
        if (wv == 0) {
#pragma unroll
            for (int i = 0; i < 8; ++i)
#pragma unroll
                for (int j = 0; j < 8; ++j)
                    acc[i][j] += redp[(r0 + i) * 64 + c0 + j];
            if (dg == 0) {
#pragma unroll
                for (int i = 0; i < 8; ++i) csum[i] += cbuf[r0 + i];
            }
        }
        __syncthreads();
    }
    if (wv == 0) {
        float* slice = part + (size_t)blockIdx.x * PSL;
#pragma unroll
        for (int i = 0; i < 8; ++i) {
            *(float4*)(slice + (r0 + i) * 64 + c0) =
                make_float4(acc[i][0], acc[i][1], acc[i][2], acc[i][3]);
            *(float4*)(slice + (r0 + i) * 64 + c0 + 4) =
                make_float4(acc[i][4], acc[i][5], acc[i][6], acc[i][7]);
        }
        if (dg == 0) {
#pragma unroll
            for (int i = 0; i < 8; ++i) slice[4096 + r0 + i] = csum[i];
        }
    }
}

// ---------------------------------------------------------------------------
// k_p3: per 64-entity tile:
//   stepA: lane owns entity row; wave owns 16 sectors (sec1^T rows via
//          wave-uniform loads). p = exp(x . sec1) max-free.
//   stepB: raw2 += p^T @ x with 8x8 register tiles; sumexp cols.
// x-tile reg-staged (T14 issue-early/write-late) into pad-68 LDS dbuf.
// 52 KiB LDS -> 3 blk/CU with launch_bounds(256,3).
// ---------------------------------------------------------------------------
__global__ __launch_bounds__(256, 3) void k_p3(
    const float* __restrict__ x, const float* __restrict__ s1t,
    float* __restrict__ part)
{
    __shared__ float xbuf[2][64 * 68];
    __shared__ float pt[64 * 68];
    const int t    = threadIdx.x;
    const int wv   = t >> 6;
    const int lane = t & 63;
    const int wu   = __builtin_amdgcn_readfirstlane(wv);
    const int sg   = (t >> 3) & 7;
    const int dg   = t & 7;

    float acc[8][8];
#pragma unroll
    for (int i = 0; i < 8; ++i)
#pragma unroll
        for (int j = 0; j < 8; ++j) acc[i][j] = 0.f;
    float sume[8];
#pragma unroll
    for (int i = 0; i < 8; ++i) sume[i] = 0.f;

    int tile = blockIdx.x;
    float4 gx[4];
    {   // prologue: load + write tile0
        const int base = tile << 6;
#pragma unroll
        for (int u = 0; u < 4; ++u) {
            const int f = t + (u << 8);
            const int ge = base + (f >> 4);
            gx[u] = (ge < EN) ? *(const float4*)(x + (size_t)ge * 64 + (f & 15) * 4)
                              : make_float4(0.f, 0.f, 0.f, 0.f);
        }
#pragma unroll
        for (int u = 0; u < 4; ++u) {
            const int f = t + (u << 8);
            *(float4*)(&xbuf[0][(f >> 4) * 68 + (f & 15) * 4]) = gx[u];
        }
    }
    __syncthreads();
    int cur = 0;
    while (tile < NT) {
        const int nxt = tile + gridDim.x;
        if (nxt < NT) {       // issue next-tile loads early; write after stepB
            const int base = nxt << 6;
#pragma unroll
            for (int u = 0; u < 4; ++u) {
                const int f = t + (u << 8);
                const int ge = base + (f >> 4);
                gx[u] = (ge < EN) ? *(const float4*)(x + (size_t)ge * 64 + (f & 15) * 4)
                                  : make_float4(0.f, 0.f, 0.f, 0.f);
            }
        }
        const int base = tile << 6;
        const bool ev = (base + lane) < EN;
        // ---- stepA: sc[j] = sum_k x[lane,k] * sec1T[k][wu*16+j] ----
        float sc[16];
#pragma unroll
        for (int j = 0; j < 16; ++j) sc[j] = 0.f;
#pragma unroll 4
        for (int kb = 0; kb < 16; ++kb) {
            const float4 xa = *(const float4*)(&xbuf[cur][lane * 68 + kb * 4]);
            const float xk[4] = {xa.x, xa.y, xa.z, xa.w};
#pragma unroll
            for (int r = 0; r < 4; ++r) {
                const float* srow = s1t + (kb * 4 + r) * 64 + wu * 16;
                const float xv = xk[r];
#pragma unroll
                for (int j = 0; j < 16; ++j) sc[j] = fmaf(xv, srow[j], sc[j]);
            }
        }
#pragma unroll
        for (int j = 0; j < 16; ++j) sc[j] = ev ? __expf(sc[j]) : 0.f;
#pragma unroll
        for (int q = 0; q < 4; ++q)
            *(float4*)(&pt[lane * 68 + wu * 16 + q * 4]) =
                make_float4(sc[q * 4], sc[q * 4 + 1], sc[q * 4 + 2], sc[q * 4 + 3]);
        __syncthreads();
        // ---- stepB: acc[a][b] += p[e, sg*8+a] * x[e, dg*8+b] ----
        if (base + 64 <= EN) {
#pragma unroll 4
            for (int i = 0; i < 16; ++i) {
                const int e = (wv << 4) + i;
                const float4 pa = *(const float4*)(&pt[e * 68 + sg * 8]);
                const float4 pb = *(const float4*)(&pt[e * 68 + sg * 8 + 4]);
                const float4 xa = *(const float4*)(&xbuf[cur][e * 68 + dg * 8]);
                const float4 xc = *(const float4*)(&xbuf[cur][e * 68 + dg * 8 + 4]);
                const float pr[8] = {pa.x, pa.y, pa.z, pa.w, pb.x, pb.y, pb.z, pb.w};
                const float xr[8] = {xa.x, xa.y, xa.z, xa.w, xc.x, xc.y, xc.z, xc.w};
#pragma unroll
                for (int a = 0; a < 8; ++a) {
#pragma unroll
                    for (int b = 0; b < 8; ++b)
                        acc[a][b] = fmaf(pr[a], xr[b], acc[a][b]);
                    sume[a] += pr[a];
                }
            }
        } else {
#pragma unroll 4
            for (int i = 0; i < 16; ++i) {
                const int e = (wv << 4) + i;
                if (base + e < EN) {
                    const float4 pa = *(const float4*)(&pt[e * 68 + sg * 8]);
                    const float4 pb = *(const float4*)(&pt[e * 68 + sg * 8 + 4]);
                    const float4 xa = *(const float4*)(&xbuf[cur][e * 68 + dg * 8]);
                    const float4 xc = *(const float4*)(&xbuf[cur][e * 68 + dg * 8 + 4]);
                    const float pr[8] = {pa.x, pa.y, pa.z, pa.w, pb.x, pb.y, pb.z, pb.w};
                    const float xr[8] = {xa.x, xa.y, xa.z, xa.w, xc.x, xc.y, xc.z, xc.w};
#pragma unroll
                    for (int a = 0; a < 8; ++a) {
#pragma unroll
                        for (int b = 0; b < 8; ++b)
                            acc[a][b] = fmaf(pr[a], xr[b], acc[a][b]);
                        sume[a] += pr[a];
                    }
                }
            }
        }
        if (nxt < NT) {       // write-late: loads had stepA+stepB to land
#pragma unroll
            for (int u = 0; u < 4; ++u) {
                const int f = t + (u << 8);
                *(float4*)(&xbuf[cur ^ 1][(f >> 4) * 68 + (f & 15) * 4]) = gx[u];
            }
        }
        __syncthreads();
        cur ^= 1;
        tile = nxt;
    }
    // reduce (reuse xbuf) + per-block partial store
    float* redp = &xbuf[0][0];
    float* cbuf = redp + 4096;
    const int r0 = sg * 8, c0 = dg * 8;
#pragma unroll
    for (int ph = 1; ph < 4; ++ph) {
        if (wv == ph) {
#pragma unroll
            for (int i = 0; i < 8; ++i) {
                *(float4*)(redp + (r0 + i) * 64 + c0) =
                    make_float4(acc[i][0], acc[i][1], acc[i][2], acc[i][3]);
                *(float4*)(redp + (r0 + i) * 64 + c0 + 4) =
                    make_float4(acc[i][4], acc[i][5], acc[i][6], acc[i][7]);
            }
            if (dg == 0) {
#pragma unroll
                for (int i = 0; i < 8; ++i) cbuf[r0 + i] = sume[i];
            }
        }
        __syncthreads();
        if (wv == 0) {
#pragma unroll
            for (int i = 0; i < 8; ++i)
#pragma unroll
                for (int j = 0; j < 8; ++j)
                    acc[i][j] += redp[(r0 + i) * 64 + c0 + j];
            if (dg == 0) {
#pragma unroll
                for (int i = 0; i < 8; ++i) sume[i] += cbuf[r0 + i];
            }
        }
        __syncthreads();
    }
    if (wv == 0) {
        float* slice = part + (size_t)blockIdx.x * PSL;
#pragma unroll
        for (int i = 0; i < 8; ++i) {
            *(float4*)(slice + (r0 + i) * 64 + c0) =
                make_float4(acc[i][0], acc[i][1], acc[i][2], acc[i][3]);
            *(float4*)(slice + (r0 + i) * 64 + c0 + 4) =
                make_float4(acc[i][4], acc[i][5], acc[i][6], acc[i][7]);
        }
        if (dg == 0) {
#pragma unroll
            for (int i = 0; i < 8; ++i) slice[4096 + r0 + i] = sume[i];
        }
    }
}

// ---------------------------------------------------------------------------
// k_p5 (REWRITTEN, tile-GEMM form — no big per-thread arrays, no scratch):
// per 64-entity tile:
//   stepA: pe = exp(x_tile . sec2^T) (lane=entity, wave=16 sectors) -> pt LDS
//   stepB: thread (eg,dg) owns 4 entities x 4 dims; runtime j-loop over 64
//          sectors: o1u += pe*G2, o2a += pe*G3, o2b += x*wotT, rs += pe.
//          Outputs: out1 = leaky(o1u/rs + c2), out2 = leaky(o2a/rs + o2b + c3).
// x read ONCE (LDS reuse for the wot term). 34.8 KiB LDS -> 4 blk/CU.
// ---------------------------------------------------------------------------
__global__ __launch_bounds__(256, 4) void k_p5(
    const float* __restrict__ x, const float* __restrict__ s2t,
    const float* __restrict__ G2, const float* __restrict__ G3,
    const float* __restrict__ wot, const float* __restrict__ c2,
    const float* __restrict__ c3, float* __restrict__ out1,
    float* __restrict__ out2)
{
    __shared__ float xbuf[64 * 68];
    __shared__ float pt[64 * 68];
    const int t    = threadIdx.x;
    const int wv   = t >> 6;
    const int lane = t & 63;
    const int wu   = __builtin_amdgcn_readfirstlane(wv);
    const int eg   = t >> 4;          // 0..15: entities eg*4..+4
    const int dg   = t & 15;          // 0..15: dims dg*4..+4

    const float4 c2v = *(const float4*)(c2 + dg * 4);
    const float4 c3v = *(const float4*)(c3 + dg * 4);

    int tile = blockIdx.x;
    float4 gx[4];
    {   // prologue: load + write tile0
        const int base = tile << 6;
#pragma unroll
        for (int u = 0; u < 4; ++u) {
            const int f = t + (u << 8);
            const int ge = base + (f >> 4);
            gx[u] = (ge < EN) ? *(const float4*)(x + (size_t)ge * 64 + (f & 15) * 4)
                              : make_float4(0.f, 0.f, 0.f, 0.f);
        }
#pragma unroll
        for (int u = 0; u < 4; ++u) {
            const int f = t + (u << 8);
            *(float4*)(&xbuf[(f >> 4) * 68 + (f & 15) * 4]) = gx[u];
        }
    }
    __syncthreads();
    while (tile < NT) {
        const int nxt = tile + gridDim.x;
        if (nxt < NT) {       // issue next-tile loads early (T14)
            const int base = nxt << 6;
#pragma unroll
            for (int u = 0; u < 4; ++u) {
                const int f = t + (u << 8);
                const int ge = base + (f >> 4);
                gx[u] = (ge < EN) ? *(const float4*)(x + (size_t)ge * 64 + (f & 15) * 4)
                                  : make_float4(0.f, 0.f, 0.f, 0.f);
            }
        }
        const int base = tile << 6;
        // ---- stepA: sc[j] = x[lane,:] . sec2[wu*16+j,:]; pe = exp(sc) ----
        float sc[16];
#pragma unroll
        for (int j = 0; j < 16; ++j) sc[j] = 0.f;
#pragma unroll 4
        for (int kb = 0; kb < 16; ++kb) {
            const float4 xa = *(const float4*)(&xbuf[lane * 68 + kb * 4]);
            const float xk[4] = {xa.x, xa.y, xa.z, xa.w};
#pragma unroll
            for (int r = 0; r < 4; ++r) {
                const float* srow = s2t + (kb * 4 + r) * 64 + wu * 16;
                const float xv = xk[r];
#pragma unroll
                for (int j = 0; j < 16; ++j) sc[j] = fmaf(xv, srow[j], sc[j]);
            }
        }
        const bool ev = (base + lane) < EN;
#pragma unroll
        for (int j = 0; j < 16; ++j) sc[j] = ev ? __expf(sc[j]) : 0.f;
#pragma unroll
        for (int q = 0; q < 4; ++q)
            *(float4*)(&pt[lane * 68 + wu * 16 + q * 4]) =
                make_float4(sc[q * 4], sc[q * 4 + 1], sc[q * 4 + 2], sc[q * 4 + 3]);
        __syncthreads();
        // ---- stepB: j-loop over sectors ----
        float o1u[4][4], o2a[4][4], o2b[4][4], rs[4];
#pragma unroll
        for (int i = 0; i < 4; ++i) {
            rs[i] = 0.f;
#pragma unroll
            for (int k = 0; k < 4; ++k) { o1u[i][k] = 0.f; o2a[i][k] = 0.f; o2b[i][k] = 0.f; }
        }
        const int e0 = eg * 4;
        const float* g2c = G2 + dg * 4;
        const float* g3c = G3 + dg * 4;
        const float* wtc = wot + dg * 4;
#pragma unroll 2
        for (int j = 0; j < 64; ++j) {
            const float4 g2 = *(const float4*)(g2c + j * 64);
            const float4 g3 = *(const float4*)(g3c + j * 64);
            const float4 wt = *(const float4*)(wtc + j * 64);
#pragma unroll
            for (int i = 0; i < 4; ++i) {
                const float p  = pt[(e0 + i) * 68 + j];
                const float xv = xbuf[(e0 + i) * 68 + j];
                rs[i] += p;
                o1u[i][0] = fmaf(p, g2.x, o1u[i][0]);
                o1u[i][1] = fmaf(p, g2.y, o1u[i][1]);
                o1u[i][2] = fmaf(p, g2.z, o1u[i][2]);
                o1u[i][3] = fmaf(p, g2.w, o1u[i][3]);
                o2a[i][0] = fmaf(p, g3.x, o2a[i][0]);
                o2a[i][1] = fmaf(p, g3.y, o2a[i][1]);
                o2a[i][2] = fmaf(p, g3.z, o2a[i][2]);
                o2a[i][3] = fmaf(p, g3.w, o2a[i][3]);
                o2b[i][0] = fmaf(xv, wt.x, o2b[i][0]);
                o2b[i][1] = fmaf(xv, wt.y, o2b[i][1]);
                o2b[i][2] = fmaf(xv, wt.z, o2b[i][2]);
                o2b[i][3] = fmaf(xv, wt.w, o2b[i][3]);
            }
        }
        __syncthreads();          // all pt/xbuf reads done
        if (nxt < NT) {           // write-late next x-tile
#pragma unroll
            for (int u = 0; u < 4; ++u) {
                const int f = t + (u << 8);
                *(float4*)(&xbuf[(f >> 4) * 68 + (f & 15) * 4]) = gx[u];
            }
        }
        // ---- outputs (coalesced: 16 dg-lanes contiguous per eg) ----
#pragma unroll
        for (int i = 0; i < 4; ++i) {
            const int e = base + e0 + i;
            if (e < EN) {
                const float r = 1.f / rs[i];
                float4 v1, v2;
                v1.x = leaky1(fmaf(o1u[i][0], r, c2v.x));
                v1.y = leaky1(fmaf(o1u[i][1], r, c2v.y));
                v1.z = leaky1(fmaf(o1u[i][2], r, c2v.z));
                v1.w = leaky1(fmaf(o1u[i][3], r, c2v.w));
                v2.x = leaky1(fmaf(o2a[i][0], r, o2b[i][0] + c3v.x));
                v2.y = leaky1(fmaf(o2a[i][1], r, o2b[i][1] + c3v.y));
                v2.z = leaky1(fmaf(o2a[i][2], r, o2b[i][2] + c3v.z));
                v2.w = leaky1(fmaf(o2a[i][3], r, o2b[i][3] + c3v.w));
                *(float4*)(out1 + (size_t)e * 64 + dg * 4) = v1;
                *(float4*)(out2 + (size_t)e * 64 + dg * 4) = v2;
            }
        }
        __syncthreads();          // xbuf ready for next stepA
        tile = nxt;
    }
}

// ---------------------------------------------------------------------------
// partial-reduce + normalize kernels (4096 threads each)
// ---------------------------------------------------------------------------
__global__ void k_norm1(const float* __restrict__ part, float* __restrict__ ws)
{
    const int gid = blockIdx.x * 256 + threadIdx.x;
    const int s = gid >> 6, d = gid & 63;
    float raw = 0.f, cs = 0.f;
#pragma unroll 16
    for (int b = 0; b < NB1; ++b) {
        raw += part[(size_t)b * PSL + gid];
        cs  += part[(size_t)b * PSL + 4096 + s];
    }
    ws[SEC1T + d * 64 + s] = raw / cs;    // transposed for k_p3 stepA
}

__global__ void k_norm2(const float* __restrict__ part, float* __restrict__ ws)
{
    const int gid = blockIdx.x * 256 + threadIdx.x;
    const int s = gid >> 6, d = gid & 63;
    float raw = 0.f, se = 0.f;
#pragma unroll 16
    for (int b = 0; b < NB2; ++b) {
        raw += part[(size_t)b * PSL + gid];
        se  += part[(size_t)b * PSL + 4096 + s];
    }
    const float v = raw / se;
    ws[SEC2 + gid] = v;
    ws[SEC2T + d * 64 + s] = v;
}

// ---------------------------------------------------------------------------
// tiny prep kernels (64x64 weight folds)
// ---------------------------------------------------------------------------
__global__ void k_prep1(const float* __restrict__ W_ent, const float* __restrict__ b_ent,
                        const float* __restrict__ Wsi, const float* __restrict__ bsi,
                        const float* __restrict__ Wso, const float* __restrict__ bso,
                        const float* __restrict__ Wout,
                        float* __restrict__ ws)
{
    const int gid = blockIdx.x * 256 + threadIdx.x;
    if (gid < 4096) {                       // M1[d][m] = (Wsi@W_ent)[d][m]
        const int d = gid >> 6, mm = gid & 63;
        float s = 0.f;
        for (int k = 0; k < 64; ++k) s = fmaf(Wsi[d * 64 + k], W_ent[k * 64 + mm], s);
        ws[M1_ + gid] = s;
    } else if (gid < 8192) {                // M2T[m][d] = (Wso@W_ent)[d][m]
        const int i = gid - 4096, mm = i >> 6, d = i & 63;
        float s = 0.f;
        for (int j = 0; j < 64; ++j) s = fmaf(W_ent[j * 64 + mm], Wso[d * 64 + j], s);
        ws[M2T_ + i] = s;
    } else if (gid < 12288) {               // WoutT[k][d] = Wout[d][k]
        const int i = gid - 8192, k = i >> 6, d = i & 63;
        ws[WOUTT + i] = Wout[d * 64 + k];
    } else if (gid < 12352) {               // c1 = Wsi@b_ent + bsi
        const int d = gid - 12288;
        float s = bsi[d];
        for (int k = 0; k < 64; ++k) s = fmaf(Wsi[d * 64 + k], b_ent[k], s);
        ws[C1_ + d] = s;
    } else if (gid < 12416) {               // c2 = Wso@b_ent + bso
        const int d = gid - 12352;
        float s = bso[d];
        for (int k = 0; k < 64; ++k) s = fmaf(Wso[d * 64 + k], b_ent[k], s);
        ws[C2_ + d] = s;
    }
}

__global__ void k_prep2(const float* __restrict__ Wout, const float* __restrict__ bout,
                        float* __restrict__ ws)
{
    const int gid = blockIdx.x * 256 + threadIdx.x;
    const float* M1p = ws + M1_;
    if (gid < 4096) {                       // M3T[m][d] = (Wout@M1)[d][m]
        const int mm = gid >> 6, d = gid & 63;
        float s = 0.f;
        for (int j = 0; j < 64; ++j) s = fmaf(Wout[d * 64 + j], M1p[j * 64 + mm], s);
        ws[M3T_ + gid] = s;
    } else if (gid < 4160) {                // c3 = Wout@c1 + bout
        const int d = gid - 4096;
        const float* c1p = ws + C1_;
        float s = bout[d];
        for (int k = 0; k < 64; ++k) s = fmaf(Wout[d * 64 + k], c1p[k], s);
        ws[C3_ + d] = s;
    }
}

__global__ void k_prepG(float* __restrict__ ws)
{
    const int gid = blockIdx.x * 256 + threadIdx.x;  // 8192 threads
    const float* sec2 = ws + SEC2;
    if (gid < 4096) {                        // G2 = sec2 @ M2^T
        const int s = gid >> 6, d = gid & 63;
        const float* m2t = ws + M2T_;
        float a = 0.f;
        for (int k = 0; k < 64; ++k) a = fmaf(sec2[s * 64 + k], m2t[k * 64 + d], a);
        ws[G2_ + gid] = a;
    } else {                                 // G3 = sec2 @ M3^T
        const int i = gid - 4096, s = i >> 6, d = i & 63;
        const float* m3t = ws + M3T_;
        float a = 0.f;
        for (int k = 0; k < 64; ++k) a = fmaf(sec2[s * 64 + k], m3t[k * 64 + d], a);
        ws[G3_ + i] = a;
    }
}

extern "C" void kernel_launch(void* const* d_in, const int* in_sizes, int n_in,
                              void* d_out, int out_size, void* d_ws, size_t ws_size,
                              hipStream_t stream)
{
    const float* x     = (const float*)d_in[0];
    const float* e2s   = (const float*)d_in[1];
    const float* W_ent = (const float*)d_in[2];
    const float* b_ent = (const float*)d_in[3];
    const float* Wsi   = (const float*)d_in[4];
    const float* bsi   = (const float*)d_in[5];
    const float* Wso   = (const float*)d_in[6];
    const float* bso   = (const float*)d_in[7];
    const float* Wout  = (const float*)d_in[8];
    const float* bout  = (const float*)d_in[9];
    float* ws  = (float*)d_ws;
    float* out = (float*)d_out;

    (void)in_sizes; (void)n_in; (void)out_size; (void)ws_size;

    // big partial buffers live in d_out; k_p5 (last) fully overwrites d_out
    float* p1 = out;                 // NB1*PSL floats
    float* p2 = out + P2_OFF;        // NB2*PSL floats

    k_prep1<<<49, 256, 0, stream>>>(W_ent, b_ent, Wsi, bsi, Wso, bso, Wout, ws);
    k_prep2<<<17, 256, 0, stream>>>(Wout, bout, ws);
    k_accum<<<NB1, 256, 0, stream>>>(e2s, x, p1);
    k_norm1<<<16, 256, 0, stream>>>(p1, ws);
    k_p3<<<NB2, 256, 0, stream>>>(x, ws + SEC1T, p2);
    k_norm2<<<16, 256, 0, stream>>>(p2, ws);
    k_prepG<<<32, 256, 0, stream>>>(ws);
    k_p5<<<1024, 256, 0, stream>>>(x, ws + SEC2T, ws + G2_, ws + G3_,
                                   ws + WOUTT, ws + C2_, ws + C3_,
                                   out, out + (size_t)EN * 64);
}